// Round 1
// baseline (24017.062 us; speedup 1.0000x reference)
//
#include <hip/hip_runtime.h>
#include <math.h>
#include <float.h>

#define B_ 128
#define T_ 80
#define D_ 4096
#define H_ 1024
#define V_ 6000
#define S_ 10
#define G3 (3*H_)

// ---------------- static device scratch ----------------
__device__ float g_gi[(size_t)B_*T_*G3];   // 125.8 MB: precomputed x@Wih^T+bih for all t
__device__ float g_gh[B_*G3];
__device__ float g_gi2[B_*G3];
__device__ float g_gh2[B_*G3];
__device__ float g_eh[B_*H_];
__device__ float g_dh[B_*H_];
__device__ float g_u[B_*H_];
__device__ float g_cat[B_*2*H_];
__device__ float g_logits[B_*V_];
__device__ int   g_word[B_];

// ---------------- generic tiled fp32 GEMM: C = act(A @ W^T + bias) ----------------
// A: [M, lda] row-major; W: [N, ldw] row-major (we dot A rows with W rows)
#define BM 64
#define BN 64
#define BK 16

__global__ __launch_bounds__(256) void gemm_wt(
    const float* __restrict__ A, int lda,
    const float* __restrict__ W, int ldw,
    const float* __restrict__ bias,
    float* __restrict__ C, int ldc,
    int M, int N, int K, int act,
    const float* __restrict__ A2,
    const float* __restrict__ W2,
    const float* __restrict__ bias2,
    float* __restrict__ C2)
{
    if (blockIdx.z == 1) { A = A2; W = W2; bias = bias2; C = C2; }

    __shared__ float As[BK][BM];
    __shared__ float Ws[BK][BN];

    const int tid = threadIdx.x;
    const int bm = blockIdx.y * BM;
    const int bn = blockIdx.x * BN;
    const int lr = tid >> 2;           // 0..63  (tile row for loads)
    const int lc = (tid & 3) << 2;     // 0,4,8,12 (k-offset for loads)
    const int tr = (tid >> 4) << 2;    // 0..60  (micro-tile row)
    const int tc = (tid & 15) << 2;    // 0..60  (micro-tile col)

    float acc[4][4] = {};

    for (int k0 = 0; k0 < K; k0 += BK) {
        // stage A tile (transposed) and W tile (transposed)
        {
            const int gr = bm + lr;
            float4 av = *(const float4*)(A + (size_t)gr * lda + k0 + lc);
            As[lc+0][lr] = av.x; As[lc+1][lr] = av.y;
            As[lc+2][lr] = av.z; As[lc+3][lr] = av.w;

            const int wr = bn + lr;
            float4 wv = make_float4(0.f, 0.f, 0.f, 0.f);
            if (wr < N) wv = *(const float4*)(W + (size_t)wr * ldw + k0 + lc);
            Ws[lc+0][lr] = wv.x; Ws[lc+1][lr] = wv.y;
            Ws[lc+2][lr] = wv.z; Ws[lc+3][lr] = wv.w;
        }
        __syncthreads();

#pragma unroll
        for (int k = 0; k < BK; ++k) {
            float4 a4 = *(const float4*)&As[k][tr];
            float4 b4 = *(const float4*)&Ws[k][tc];
            float ar[4] = {a4.x, a4.y, a4.z, a4.w};
            float br[4] = {b4.x, b4.y, b4.z, b4.w};
#pragma unroll
            for (int i = 0; i < 4; ++i)
#pragma unroll
                for (int j = 0; j < 4; ++j)
                    acc[i][j] = fmaf(ar[i], br[j], acc[i][j]);
        }
        __syncthreads();
    }

#pragma unroll
    for (int i = 0; i < 4; ++i) {
        const int m = bm + tr + i;
#pragma unroll
        for (int j = 0; j < 4; ++j) {
            const int n = bn + tc + j;
            if (n < N) {
                float v = acc[i][j];
                if (bias) v += bias[n];
                if (act)  v = fmaxf(v, 0.f);
                C[(size_t)m * ldc + n] = v;
            }
        }
    }
}

// ---------------- GRU elementwise update ----------------
// h' = (1-z)*n + z*h ; r=sig(ir+hr), z=sig(iz+hz), n=tanh(inn + r*hn)
// GI row stride 0 => broadcast bias-only input gates (decoder eh update)
__global__ __launch_bounds__(256) void gru_update(
    const float* __restrict__ GI, int gi_rstride,
    const float* __restrict__ GH,
    float* __restrict__ h)
{
    const int idx = blockIdx.x * 256 + threadIdx.x;   // B*H threads
    const int b = idx >> 10;
    const int j = idx & (H_ - 1);
    const float* gi = GI + (size_t)b * gi_rstride;
    const float* gh = GH + (size_t)b * G3;
    const float ir = gi[j], iz = gi[H_ + j], inn = gi[2*H_ + j];
    const float hr = gh[j], hz = gh[H_ + j], hn = gh[2*H_ + j];
    const float r = 1.f / (1.f + expf(-(ir + hr)));
    const float z = 1.f / (1.f + expf(-(iz + hz)));
    const float n = tanhf(inn + r * hn);
    h[idx] = (1.f - z) * n + z * h[idx];
}

// ---------------- concat [eh | embed[word]] ----------------
__global__ __launch_bounds__(256) void cat_eh_emb(
    const float* __restrict__ eh,
    const float* __restrict__ embed,
    const int* __restrict__ word,
    float* __restrict__ cat)
{
    const int idx = blockIdx.x * 256 + threadIdx.x;   // B*2H
    const int b = idx >> 11;
    const int j = idx & (2*H_ - 1);
    float v;
    if (j < H_) v = eh[b * H_ + j];
    else        v = embed[(size_t)word[b] * H_ + (j - H_)];
    cat[idx] = v;
}

// ---------------- init state ----------------
__global__ __launch_bounds__(256) void init_state(
    float* __restrict__ eh, float* __restrict__ dh,
    int* __restrict__ word, float* __restrict__ out)
{
    const int idx = blockIdx.x * 256 + threadIdx.x;
    if (idx < B_*H_) { eh[idx] = 0.f; dh[idx] = 0.f; }
    if (idx < B_)    word[idx] = 1;
    if (idx < 21)    out[idx] = 0.f;
}

// ---------------- log-softmax + argmax + loss (one block per row) ----------------
__global__ __launch_bounds__(256) void softmax_loss(
    const float* __restrict__ logits,
    const int* __restrict__ target,
    int s,
    int* __restrict__ word,
    float* __restrict__ out)
{
    const int b = blockIdx.x;
    const int t = threadIdx.x;
    const float* row = logits + (size_t)b * V_;

    __shared__ float sv[256];
    __shared__ int   si[256];
    __shared__ float ss[256];

    float best = -FLT_MAX; int bi = 0;
    for (int j = t; j < V_; j += 256) {
        float v = row[j];
        if (v > best) { best = v; bi = j; }
    }
    sv[t] = best; si[t] = bi;
    __syncthreads();
    for (int off = 128; off > 0; off >>= 1) {
        if (t < off) {
            float v2 = sv[t + off]; int i2 = si[t + off];
            if (v2 > sv[t] || (v2 == sv[t] && i2 < si[t])) { sv[t] = v2; si[t] = i2; }
        }
        __syncthreads();
    }
    const float m = sv[0];
    const int amax = si[0];

    float sum = 0.f;
    for (int j = t; j < V_; j += 256) sum += expf(row[j] - m);
    ss[t] = sum;
    __syncthreads();
    for (int off = 128; off > 0; off >>= 1) {
        if (t < off) ss[t] += ss[t + off];
        __syncthreads();
    }

    if (t == 0) {
        const float lse = m + logf(ss[0]);
        const int tgt = target[b * S_ + s];
        const float logp = row[tgt] - lse;
        atomicAdd(&out[0], -logp * (1.0f / (float)B_));
        word[b] = amax;
        if (b == 0) out[1 + s]  = (float)amax;
        if (b == 1) out[11 + s] = (float)amax;
    }
}

// ---------------- host launcher ----------------
static inline void launch_gemm(hipStream_t stream,
    const float* A, int lda, const float* W, int ldw, const float* bias,
    float* C, int ldc, int M, int N, int K, int act)
{
    dim3 grid((N + BN - 1) / BN, M / BM, 1);
    gemm_wt<<<grid, 256, 0, stream>>>(A, lda, W, ldw, bias, C, ldc, M, N, K, act,
                                      nullptr, nullptr, nullptr, nullptr);
}

static inline void launch_gemm_dual(hipStream_t stream,
    const float* A, int lda, const float* W, int ldw, const float* bias, float* C,
    const float* A2, const float* W2, const float* bias2, float* C2,
    int ldc, int M, int N, int K)
{
    dim3 grid((N + BN - 1) / BN, M / BM, 2);
    gemm_wt<<<grid, 256, 0, stream>>>(A, lda, W, ldw, bias, C, ldc, M, N, K, 0,
                                      A2, W2, bias2, C2);
}

extern "C" void kernel_launch(void* const* d_in, const int* in_sizes, int n_in,
                              void* d_out, int out_size, void* d_ws, size_t ws_size,
                              hipStream_t stream)
{
    const float* data    = (const float*)d_in[0];
    const int*   target  = (const int*)  d_in[2];
    const float* enc_Wih = (const float*)d_in[4];
    const float* enc_Whh = (const float*)d_in[5];
    const float* enc_bih = (const float*)d_in[6];
    const float* enc_bhh = (const float*)d_in[7];
    const float* dec_Wih = (const float*)d_in[8];
    const float* dec_Whh = (const float*)d_in[9];
    const float* dec_bih = (const float*)d_in[10];
    const float* dec_bhh = (const float*)d_in[11];
    const float* lin1_W  = (const float*)d_in[12];
    const float* lin1_b  = (const float*)d_in[13];
    const float* lin2_W  = (const float*)d_in[14];
    const float* lin2_b  = (const float*)d_in[15];
    const float* embed   = (const float*)d_in[16];
    float* out = (float*)d_out;

    float *gi, *gh, *gi2, *gh2, *eh, *dh, *u, *cat, *logits; int* word;
    hipGetSymbolAddress((void**)&gi,     HIP_SYMBOL(g_gi));
    hipGetSymbolAddress((void**)&gh,     HIP_SYMBOL(g_gh));
    hipGetSymbolAddress((void**)&gi2,    HIP_SYMBOL(g_gi2));
    hipGetSymbolAddress((void**)&gh2,    HIP_SYMBOL(g_gh2));
    hipGetSymbolAddress((void**)&eh,     HIP_SYMBOL(g_eh));
    hipGetSymbolAddress((void**)&dh,     HIP_SYMBOL(g_dh));
    hipGetSymbolAddress((void**)&u,      HIP_SYMBOL(g_u));
    hipGetSymbolAddress((void**)&cat,    HIP_SYMBOL(g_cat));
    hipGetSymbolAddress((void**)&logits, HIP_SYMBOL(g_logits));
    hipGetSymbolAddress((void**)&word,   HIP_SYMBOL(g_word));

    init_state<<<512, 256, 0, stream>>>(eh, dh, word, out);

    // Precompute input gates for ALL encoder timesteps: [B*T, 3H]
    launch_gemm(stream, data, D_, enc_Wih, D_, enc_bih, gi, G3, B_*T_, G3, D_, 0);

    // ---------------- encoder scan ----------------
    for (int t = 0; t < T_; ++t) {
        launch_gemm(stream, eh, H_, enc_Whh, H_, enc_bhh, gh, G3, B_, G3, H_, 0);
        gru_update<<<512, 256, 0, stream>>>(gi + (size_t)t * G3, T_ * G3, gh, eh);
        // u = relu(eh @ W1a^T + lin1_b)   (W1a = lin1_W[:, :H], row stride 2H)
        launch_gemm(stream, eh, H_, lin1_W, 2*H_, lin1_b, u, H_, B_, H_, H_, 1);
        launch_gemm_dual(stream, u,  H_, dec_Wih, H_, dec_bih, gi2,
                                 dh, dec_Whh, dec_bhh, gh2, G3, B_, G3, H_);
        gru_update<<<512, 256, 0, stream>>>(gi2, G3, gh2, dh);
    }

    // ---------------- decoder scan ----------------
    for (int s = 0; s < S_; ++s) {
        launch_gemm(stream, eh, H_, enc_Whh, H_, enc_bhh, gh, G3, B_, G3, H_, 0);
        gru_update<<<512, 256, 0, stream>>>(enc_bih, 0, gh, eh);  // gi = bias broadcast
        cat_eh_emb<<<1024, 256, 0, stream>>>(eh, embed, word, cat);
        // u = relu([eh|emb] @ lin1_W^T + lin1_b)   (K = 2H)
        launch_gemm(stream, cat, 2*H_, lin1_W, 2*H_, lin1_b, u, H_, B_, H_, 2*H_, 1);
        launch_gemm_dual(stream, u,  H_, dec_Wih, H_, dec_bih, gi2,
                                 dh, dec_Whh, dec_bhh, gh2, G3, B_, G3, H_);
        gru_update<<<512, 256, 0, stream>>>(gi2, G3, gh2, dh);
        launch_gemm(stream, dh, H_, lin2_W, H_, lin2_b, logits, V_, B_, V_, H_, 0);
        softmax_loss<<<B_, 256, 0, stream>>>(logits, target, s, word, out);
    }
}

// Round 2
// 8727.711 us; speedup vs baseline: 2.7518x; 2.7518x over previous
//
#include <hip/hip_runtime.h>
#include <math.h>
#include <float.h>

#define B_ 128
#define T_ 80
#define D_ 4096
#define H_ 1024
#define V_ 6000
#define S_ 10
#define G3 (3*H_)
#define KSPLIT 4

typedef unsigned short ushort_t;
typedef __attribute__((ext_vector_type(8))) unsigned short u16x8;
typedef __attribute__((ext_vector_type(8))) short s16x8;
typedef __attribute__((ext_vector_type(4))) float fx4;

// ---------------- static device scratch ----------------
__device__ float    g_gi[(size_t)B_*T_*G3];        // precomputed x@Wih^T+bih, all t
__device__ ushort_t g_Ah[(size_t)B_*T_*D_];        // data hi (bf16 bits)
__device__ ushort_t g_Al[(size_t)B_*T_*D_];        // data lo
__device__ ushort_t g_Bh[(size_t)G3*D_];           // enc_Wih hi
__device__ ushort_t g_Bl[(size_t)G3*D_];           // enc_Wih lo
__device__ float g_ghp [KSPLIT*B_*G3];             // split-K partials
__device__ float g_gi2p[KSPLIT*B_*G3];
__device__ float g_gh2p[KSPLIT*B_*G3];
__device__ float g_up  [KSPLIT*B_*H_];
__device__ float g_eh[B_*H_];
__device__ float g_dh[B_*H_];
__device__ float g_u[B_*H_];
__device__ float g_cat[B_*2*H_];
__device__ float g_logits[B_*V_];
__device__ int   g_word[B_];

// ---------------- fp32 -> bf16 hi/lo split (RNE) ----------------
__device__ inline void split1(float x, ushort_t& hi, ushort_t& lo) {
    unsigned u = __float_as_uint(x);
    unsigned rh = u + 0x7FFF + ((u >> 16) & 1);
    hi = (ushort_t)(rh >> 16);
    float fhi = __uint_as_float((unsigned)hi << 16);
    float d = x - fhi;
    unsigned u2 = __float_as_uint(d);
    unsigned rl = u2 + 0x7FFF + ((u2 >> 16) & 1);
    lo = (ushort_t)(rl >> 16);
}

__global__ __launch_bounds__(256) void split_bf16(
    const float* __restrict__ x, ushort_t* __restrict__ hi,
    ushort_t* __restrict__ lo, int n4)
{
    int i = blockIdx.x * 256 + threadIdx.x;
    if (i >= n4) return;
    float4 v = ((const float4*)x)[i];
    ushort_t h0,h1,h2,h3,l0,l1,l2,l3;
    split1(v.x,h0,l0); split1(v.y,h1,l1); split1(v.z,h2,l2); split1(v.w,h3,l3);
    u16x8 dummy;
    ushort_t* hp = hi + (size_t)i*4;  hp[0]=h0; hp[1]=h1; hp[2]=h2; hp[3]=h3;
    ushort_t* lp = lo + (size_t)i*4;  lp[0]=l0; lp[1]=l1; lp[2]=l2; lp[3]=l3;
    (void)dummy;
}

// ---------------- bf16x3 MFMA GEMM: C = (Ah+Al)@(Bh+Bl)^T + bias ----------------
// A: [M][K] bf16 hi/lo, B: [N][K] bf16 hi/lo, C: [M][N] fp32.  M,N mult of 128, K mult of 32.
__global__ __launch_bounds__(256) void gemm_mfma_x3(
    const ushort_t* __restrict__ Ahg, const ushort_t* __restrict__ Alg,
    const ushort_t* __restrict__ Bhg, const ushort_t* __restrict__ Blg,
    const float* __restrict__ bias, float* __restrict__ C, int N, int K)
{
    __shared__ ushort_t sAh[128*32], sAl[128*32], sBh[128*32], sBl[128*32];
    const int tid  = threadIdx.x;
    const int bm   = blockIdx.y * 128, bn = blockIdx.x * 128;
    const int wave = tid >> 6, lane = tid & 63;
    const int wr   = (wave >> 1) * 64, wc = (wave & 1) * 64;
    const int r    = lane & 15, g = lane >> 4;

    fx4 acc[4][4] = {};

    for (int k0 = 0; k0 < K; k0 += 32) {
        __syncthreads();
#pragma unroll
        for (int i = 0; i < 2; ++i) {
            const int o   = (tid + i*256) * 16;    // byte offset in 8 kB tile
            const int row = o >> 6;
            const int el  = (o & 63) >> 1;
            const size_t ga = (size_t)(bm + row) * K + k0 + el;
            const size_t gb = (size_t)(bn + row) * K + k0 + el;
            u16x8 vah = *(const u16x8*)(Ahg + ga);
            u16x8 val = *(const u16x8*)(Alg + ga);
            u16x8 vbh = *(const u16x8*)(Bhg + gb);
            u16x8 vbl = *(const u16x8*)(Blg + gb);
            const int lo2 = o >> 1;
            *(u16x8*)&sAh[lo2] = vah;
            *(u16x8*)&sAl[lo2] = val;
            *(u16x8*)&sBh[lo2] = vbh;
            *(u16x8*)&sBl[lo2] = vbl;
        }
        __syncthreads();

        s16x8 ah[4], al[4], bh[4], bl[4];
#pragma unroll
        for (int i = 0; i < 4; ++i) {
            const int ao = (wr + i*16 + r)*32 + g*8;
            const int bo = (wc + i*16 + r)*32 + g*8;
            ah[i] = *(const s16x8*)&sAh[ao];
            al[i] = *(const s16x8*)&sAl[ao];
            bh[i] = *(const s16x8*)&sBh[bo];
            bl[i] = *(const s16x8*)&sBl[bo];
        }
#pragma unroll
        for (int i = 0; i < 4; ++i)
#pragma unroll
            for (int j = 0; j < 4; ++j) {
                acc[i][j] = __builtin_amdgcn_mfma_f32_16x16x32_bf16(ah[i], bh[j], acc[i][j], 0, 0, 0);
                acc[i][j] = __builtin_amdgcn_mfma_f32_16x16x32_bf16(al[i], bh[j], acc[i][j], 0, 0, 0);
                acc[i][j] = __builtin_amdgcn_mfma_f32_16x16x32_bf16(ah[i], bl[j], acc[i][j], 0, 0, 0);
            }
    }

#pragma unroll
    for (int i = 0; i < 4; ++i)
#pragma unroll
        for (int j = 0; j < 4; ++j)
#pragma unroll
            for (int reg = 0; reg < 4; ++reg) {
                const int row = bm + wr + i*16 + g*4 + reg;
                const int col = bn + wc + j*16 + r;
                C[(size_t)row * N + col] = acc[i][j][reg] + bias[col];
            }
}

// ---------------- fp32 tiled GEMM (full-K, N-guarded) — logits only ----------------
#define BM 64
#define BN 64
#define BK 16

__global__ __launch_bounds__(256) void gemm_wt(
    const float* __restrict__ A, int lda,
    const float* __restrict__ W, int ldw,
    const float* __restrict__ bias,
    float* __restrict__ C, int ldc,
    int M, int N, int K)
{
    __shared__ float As[BK][BM];
    __shared__ float Ws[BK][BN];
    const int tid = threadIdx.x;
    const int bm = blockIdx.y * BM;
    const int bn = blockIdx.x * BN;
    const int lr = tid >> 2;
    const int lc = (tid & 3) << 2;
    const int tr = (tid >> 4) << 2;
    const int tc = (tid & 15) << 2;

    float acc[4][4] = {};
    for (int k0 = 0; k0 < K; k0 += BK) {
        {
            const int gr = bm + lr;
            float4 av = *(const float4*)(A + (size_t)gr * lda + k0 + lc);
            As[lc+0][lr] = av.x; As[lc+1][lr] = av.y;
            As[lc+2][lr] = av.z; As[lc+3][lr] = av.w;
            const int wr2 = bn + lr;
            float4 wv = make_float4(0.f,0.f,0.f,0.f);
            if (wr2 < N) wv = *(const float4*)(W + (size_t)wr2 * ldw + k0 + lc);
            Ws[lc+0][lr] = wv.x; Ws[lc+1][lr] = wv.y;
            Ws[lc+2][lr] = wv.z; Ws[lc+3][lr] = wv.w;
        }
        __syncthreads();
#pragma unroll
        for (int k = 0; k < BK; ++k) {
            float4 a4 = *(const float4*)&As[k][tr];
            float4 b4 = *(const float4*)&Ws[k][tc];
            float ar[4] = {a4.x,a4.y,a4.z,a4.w};
            float br[4] = {b4.x,b4.y,b4.z,b4.w};
#pragma unroll
            for (int i = 0; i < 4; ++i)
#pragma unroll
                for (int j = 0; j < 4; ++j)
                    acc[i][j] = fmaf(ar[i], br[j], acc[i][j]);
        }
        __syncthreads();
    }
#pragma unroll
    for (int i = 0; i < 4; ++i) {
        const int m = bm + tr + i;
#pragma unroll
        for (int j = 0; j < 4; ++j) {
            const int n = bn + tc + j;
            if (n < N) C[(size_t)m * ldc + n] = acc[i][j] + bias[n];
        }
    }
}

// ---------------- fp32 split-K GEMM (no bias): Cp[s][M][N], s = K-chunk ----------------
__global__ __launch_bounds__(256) void gemm_wt_sk(
    const float* __restrict__ A, int lda,
    const float* __restrict__ W, int ldw,
    float* __restrict__ Cp,
    const float* __restrict__ A2,
    const float* __restrict__ W2,
    float* __restrict__ Cp2,
    int M, int N, int K)
{
    const int z = blockIdx.z;
    const int s = z & (KSPLIT - 1);
    if (z >= KSPLIT) { A = A2; W = W2; Cp = Cp2; }

    __shared__ float As[BK][BM];
    __shared__ float Ws[BK][BN];
    const int tid = threadIdx.x;
    const int bm = blockIdx.y * BM;
    const int bn = blockIdx.x * BN;
    const int lr = tid >> 2;
    const int lc = (tid & 3) << 2;
    const int tr = (tid >> 4) << 2;
    const int tc = (tid & 15) << 2;
    const int kc = K / KSPLIT;
    const int kbeg = s * kc;

    float acc[4][4] = {};
    for (int k0 = kbeg; k0 < kbeg + kc; k0 += BK) {
        {
            const int gr = bm + lr;
            float4 av = *(const float4*)(A + (size_t)gr * lda + k0 + lc);
            As[lc+0][lr] = av.x; As[lc+1][lr] = av.y;
            As[lc+2][lr] = av.z; As[lc+3][lr] = av.w;
            const int wr2 = bn + lr;
            float4 wv = *(const float4*)(W + (size_t)wr2 * ldw + k0 + lc);
            Ws[lc+0][lr] = wv.x; Ws[lc+1][lr] = wv.y;
            Ws[lc+2][lr] = wv.z; Ws[lc+3][lr] = wv.w;
        }
        __syncthreads();
#pragma unroll
        for (int k = 0; k < BK; ++k) {
            float4 a4 = *(const float4*)&As[k][tr];
            float4 b4 = *(const float4*)&Ws[k][tc];
            float ar[4] = {a4.x,a4.y,a4.z,a4.w};
            float br[4] = {b4.x,b4.y,b4.z,b4.w};
#pragma unroll
            for (int i = 0; i < 4; ++i)
#pragma unroll
                for (int j = 0; j < 4; ++j)
                    acc[i][j] = fmaf(ar[i], br[j], acc[i][j]);
        }
        __syncthreads();
    }
    float* Cs = Cp + (size_t)s * M * N;
#pragma unroll
    for (int i = 0; i < 4; ++i) {
        const int m = bm + tr + i;
#pragma unroll
        for (int j = 0; j < 4; ++j)
            Cs[(size_t)m * N + bn + tc + j] = acc[i][j];
    }
}

// ---------------- GRU update with split-K combine ----------------
// gi_nsplit==0: GI is full rows (already biased), row stride gi_rstride (0 = broadcast)
// gi_nsplit==KSPLIT: GI partials [KSPLIT][B][3H] + bih
__global__ __launch_bounds__(256) void gru_update2(
    const float* __restrict__ GI, int gi_rstride, int gi_nsplit,
    const float* __restrict__ bih,
    const float* __restrict__ GHp, const float* __restrict__ bhh,
    float* __restrict__ h)
{
    const int idx = blockIdx.x * 256 + threadIdx.x;
    const int b = idx >> 10;
    const int j = idx & (H_ - 1);
    float ir, iz, inn;
    if (gi_nsplit == 0) {
        const float* gi = GI + (size_t)b * gi_rstride;
        ir = gi[j]; iz = gi[H_ + j]; inn = gi[2*H_ + j];
    } else {
        ir = bih[j]; iz = bih[H_ + j]; inn = bih[2*H_ + j];
        const float* p = GI + (size_t)b * G3;
#pragma unroll
        for (int s = 0; s < KSPLIT; ++s) {
            ir += p[j]; iz += p[H_ + j]; inn += p[2*H_ + j];
            p += (size_t)B_ * G3;
        }
    }
    float hr = bhh[j], hz = bhh[H_ + j], hn = bhh[2*H_ + j];
    const float* q = GHp + (size_t)b * G3;
#pragma unroll
    for (int s = 0; s < KSPLIT; ++s) {
        hr += q[j]; hz += q[H_ + j]; hn += q[2*H_ + j];
        q += (size_t)B_ * G3;
    }
    const float rg = 1.f / (1.f + expf(-(ir + hr)));
    const float zg = 1.f / (1.f + expf(-(iz + hz)));
    const float ng = tanhf(inn + rg * hn);
    h[idx] = (1.f - zg) * ng + zg * h[idx];
}

// ---------------- relu(sum partials + bias) ----------------
__global__ __launch_bounds__(256) void relu_combine(
    const float* __restrict__ Up, const float* __restrict__ bias,
    float* __restrict__ u)
{
    const int idx = blockIdx.x * 256 + threadIdx.x;  // B*H
    const int j = idx & (H_ - 1);
    float v = bias[j];
#pragma unroll
    for (int s = 0; s < KSPLIT; ++s) v += Up[(size_t)s * B_ * H_ + idx];
    u[idx] = fmaxf(v, 0.f);
}

// ---------------- concat [eh | embed[word]] ----------------
__global__ __launch_bounds__(256) void cat_eh_emb(
    const float* __restrict__ eh, const float* __restrict__ embed,
    const int* __restrict__ word, float* __restrict__ cat)
{
    const int idx = blockIdx.x * 256 + threadIdx.x;
    const int b = idx >> 11;
    const int j = idx & (2*H_ - 1);
    float v;
    if (j < H_) v = eh[b * H_ + j];
    else        v = embed[(size_t)word[b] * H_ + (j - H_)];
    cat[idx] = v;
}

// ---------------- init ----------------
__global__ __launch_bounds__(256) void init_state(
    float* __restrict__ eh, float* __restrict__ dh,
    int* __restrict__ word, float* __restrict__ out)
{
    const int idx = blockIdx.x * 256 + threadIdx.x;
    if (idx < B_*H_) { eh[idx] = 0.f; dh[idx] = 0.f; }
    if (idx < B_)    word[idx] = 1;
    if (idx < 21)    out[idx] = 0.f;
}

// ---------------- log-softmax + argmax + loss ----------------
__global__ __launch_bounds__(256) void softmax_loss(
    const float* __restrict__ logits, const int* __restrict__ target,
    int s, int* __restrict__ word, float* __restrict__ out)
{
    const int b = blockIdx.x;
    const int t = threadIdx.x;
    const float* row = logits + (size_t)b * V_;
    __shared__ float sv[256];
    __shared__ int   si[256];
    __shared__ float ss[256];

    float best = -FLT_MAX; int bi = 0;
    for (int j = t; j < V_; j += 256) {
        float v = row[j];
        if (v > best) { best = v; bi = j; }
    }
    sv[t] = best; si[t] = bi;
    __syncthreads();
    for (int off = 128; off > 0; off >>= 1) {
        if (t < off) {
            float v2 = sv[t + off]; int i2 = si[t + off];
            if (v2 > sv[t] || (v2 == sv[t] && i2 < si[t])) { sv[t] = v2; si[t] = i2; }
        }
        __syncthreads();
    }
    const float m = sv[0];
    const int amax = si[0];

    float sum = 0.f;
    for (int j = t; j < V_; j += 256) sum += expf(row[j] - m);
    ss[t] = sum;
    __syncthreads();
    for (int off = 128; off > 0; off >>= 1) {
        if (t < off) ss[t] += ss[t + off];
        __syncthreads();
    }
    if (t == 0) {
        const float lse = m + logf(ss[0]);
        const int tgt = target[b * S_ + s];
        const float logp = row[tgt] - lse;
        atomicAdd(&out[0], -logp * (1.0f / (float)B_));
        word[b] = amax;
        if (b == 0) out[1 + s]  = (float)amax;
        if (b == 1) out[11 + s] = (float)amax;
    }
}

// ---------------- host ----------------
extern "C" void kernel_launch(void* const* d_in, const int* in_sizes, int n_in,
                              void* d_out, int out_size, void* d_ws, size_t ws_size,
                              hipStream_t stream)
{
    const float* data    = (const float*)d_in[0];
    const int*   target  = (const int*)  d_in[2];
    const float* enc_Wih = (const float*)d_in[4];
    const float* enc_Whh = (const float*)d_in[5];
    const float* enc_bih = (const float*)d_in[6];
    const float* enc_bhh = (const float*)d_in[7];
    const float* dec_Wih = (const float*)d_in[8];
    const float* dec_Whh = (const float*)d_in[9];
    const float* dec_bih = (const float*)d_in[10];
    const float* dec_bhh = (const float*)d_in[11];
    const float* lin1_W  = (const float*)d_in[12];
    const float* lin1_b  = (const float*)d_in[13];
    const float* lin2_W  = (const float*)d_in[14];
    const float* lin2_b  = (const float*)d_in[15];
    const float* embed   = (const float*)d_in[16];
    float* out = (float*)d_out;

    float *gi, *eh, *dh, *u, *cat, *logits, *ghp, *gi2p, *gh2p, *up;
    ushort_t *Ah, *Al, *Bh, *Bl; int* word;
    hipGetSymbolAddress((void**)&gi,     HIP_SYMBOL(g_gi));
    hipGetSymbolAddress((void**)&Ah,     HIP_SYMBOL(g_Ah));
    hipGetSymbolAddress((void**)&Al,     HIP_SYMBOL(g_Al));
    hipGetSymbolAddress((void**)&Bh,     HIP_SYMBOL(g_Bh));
    hipGetSymbolAddress((void**)&Bl,     HIP_SYMBOL(g_Bl));
    hipGetSymbolAddress((void**)&ghp,    HIP_SYMBOL(g_ghp));
    hipGetSymbolAddress((void**)&gi2p,   HIP_SYMBOL(g_gi2p));
    hipGetSymbolAddress((void**)&gh2p,   HIP_SYMBOL(g_gh2p));
    hipGetSymbolAddress((void**)&up,     HIP_SYMBOL(g_up));
    hipGetSymbolAddress((void**)&eh,     HIP_SYMBOL(g_eh));
    hipGetSymbolAddress((void**)&dh,     HIP_SYMBOL(g_dh));
    hipGetSymbolAddress((void**)&u,      HIP_SYMBOL(g_u));
    hipGetSymbolAddress((void**)&cat,    HIP_SYMBOL(g_cat));
    hipGetSymbolAddress((void**)&logits, HIP_SYMBOL(g_logits));
    hipGetSymbolAddress((void**)&word,   HIP_SYMBOL(g_word));

    init_state<<<512, 256, 0, stream>>>(eh, dh, word, out);

    // bf16 hi/lo splits for the big precompute GEMM
    split_bf16<<<(B_*T_*D_/4 + 255)/256, 256, 0, stream>>>(data,    Ah, Al, B_*T_*D_/4);
    split_bf16<<<(G3*D_/4   + 255)/256, 256, 0, stream>>>(enc_Wih, Bh, Bl, G3*D_/4);

    // gi[B*T][3H] = data @ enc_Wih^T + enc_bih  (bf16x3 MFMA)
    {
        dim3 grid(G3/128, (B_*T_)/128, 1);
        gemm_mfma_x3<<<grid, 256, 0, stream>>>(Ah, Al, Bh, Bl, enc_bih, gi, G3, D_);
    }

    // ---------------- encoder scan ----------------
    for (int t = 0; t < T_; ++t) {
        { dim3 grid(G3/BN, B_/BM, KSPLIT);
          gemm_wt_sk<<<grid, 256, 0, stream>>>(eh, H_, enc_Whh, H_, ghp,
                                               nullptr, nullptr, nullptr, B_, G3, H_); }
        gru_update2<<<512, 256, 0, stream>>>(gi + (size_t)t * G3, T_ * G3, 0, nullptr,
                                             ghp, enc_bhh, eh);
        { dim3 grid(H_/BN, B_/BM, KSPLIT);
          gemm_wt_sk<<<grid, 256, 0, stream>>>(eh, H_, lin1_W, 2*H_, up,
                                               nullptr, nullptr, nullptr, B_, H_, H_); }
        relu_combine<<<512, 256, 0, stream>>>(up, lin1_b, u);
        { dim3 grid(G3/BN, B_/BM, 2*KSPLIT);
          gemm_wt_sk<<<grid, 256, 0, stream>>>(u, H_, dec_Wih, H_, gi2p,
                                               dh, dec_Whh, gh2p, B_, G3, H_); }
        gru_update2<<<512, 256, 0, stream>>>(gi2p, 0, KSPLIT, dec_bih,
                                             gh2p, dec_bhh, dh);
    }

    // ---------------- decoder scan ----------------
    for (int s = 0; s < S_; ++s) {
        { dim3 grid(G3/BN, B_/BM, KSPLIT);
          gemm_wt_sk<<<grid, 256, 0, stream>>>(eh, H_, enc_Whh, H_, ghp,
                                               nullptr, nullptr, nullptr, B_, G3, H_); }
        gru_update2<<<512, 256, 0, stream>>>(enc_bih, 0, 0, nullptr,
                                             ghp, enc_bhh, eh);
        cat_eh_emb<<<1024, 256, 0, stream>>>(eh, embed, word, cat);
        { dim3 grid(H_/BN, B_/BM, KSPLIT);
          gemm_wt_sk<<<grid, 256, 0, stream>>>(cat, 2*H_, lin1_W, 2*H_, up,
                                               nullptr, nullptr, nullptr, B_, H_, 2*H_); }
        relu_combine<<<512, 256, 0, stream>>>(up, lin1_b, u);
        { dim3 grid(G3/BN, B_/BM, 2*KSPLIT);
          gemm_wt_sk<<<grid, 256, 0, stream>>>(u, H_, dec_Wih, H_, gi2p,
                                               dh, dec_Whh, gh2p, B_, G3, H_); }
        gru_update2<<<512, 256, 0, stream>>>(gi2p, 0, KSPLIT, dec_bih,
                                             gh2p, dec_bhh, dh);
        { dim3 grid((V_+BN-1)/BN, B_/BM, 1);
          gemm_wt<<<grid, 256, 0, stream>>>(dh, H_, lin2_W, H_, lin2_b, logits, V_, B_, V_, H_); }
        softmax_loss<<<B_, 256, 0, stream>>>(logits, target, s, word, out);
    }
}

// Round 3
// 7507.805 us; speedup vs baseline: 3.1989x; 1.1625x over previous
//
#include <hip/hip_runtime.h>
#include <math.h>
#include <float.h>

#define B_ 128
#define T_ 80
#define D_ 4096
#define H_ 1024
#define V_ 6000
#define S_ 10
#define G3 (3*H_)
#define KSPLIT 4

typedef unsigned short ushort_t;
typedef __attribute__((ext_vector_type(8))) short s16x8;
typedef __attribute__((ext_vector_type(4))) float fx4;

// ---------------- static device scratch ----------------
__device__ float    g_gi[(size_t)B_*T_*G3];        // precomputed x@Wih^T+bih, all t
__device__ ushort_t g_Ah[(size_t)B_*T_*D_];        // data hi (bf16 bits)
__device__ ushort_t g_Al[(size_t)B_*T_*D_];        // data lo
__device__ ushort_t g_Bh[(size_t)G3*D_];           // enc_Wih hi
__device__ ushort_t g_Bl[(size_t)G3*D_];           // enc_Wih lo
__device__ ushort_t g_Whh_h[G3*H_],  g_Whh_l[G3*H_];     // enc_Whh
__device__ ushort_t g_dWih_h[G3*H_], g_dWih_l[G3*H_];    // dec_Wih
__device__ ushort_t g_dWhh_h[G3*H_], g_dWhh_l[G3*H_];    // dec_Whh
__device__ ushort_t g_l1h[H_*2*H_],  g_l1l[H_*2*H_];     // lin1_W (full [H][2H])
__device__ float g_ghp [KSPLIT*B_*G3];             // split-K partials
__device__ float g_gi2p[KSPLIT*B_*G3];
__device__ float g_gh2p[KSPLIT*B_*G3];
__device__ float g_up  [KSPLIT*B_*H_];
__device__ float g_eh[B_*H_];
__device__ float g_dh[B_*H_];
__device__ ushort_t g_ehh[B_*H_], g_ehl[B_*H_];
__device__ ushort_t g_dhh[B_*H_], g_dhl[B_*H_];
__device__ ushort_t g_uh[B_*H_],  g_ul[B_*H_];
__device__ ushort_t g_cath[B_*2*H_], g_catl[B_*2*H_];
__device__ float g_logits[B_*V_];
__device__ int   g_word[B_];

// ---------------- fp32 -> bf16 hi/lo split (RNE) ----------------
__device__ inline void split1(float x, ushort_t& hi, ushort_t& lo) {
    unsigned u = __float_as_uint(x);
    unsigned rh = u + 0x7FFF + ((u >> 16) & 1);
    hi = (ushort_t)(rh >> 16);
    float fhi = __uint_as_float((unsigned)hi << 16);
    float d = x - fhi;
    unsigned u2 = __float_as_uint(d);
    unsigned rl = u2 + 0x7FFF + ((u2 >> 16) & 1);
    lo = (ushort_t)(rl >> 16);
}

__global__ __launch_bounds__(256) void split_bf16(
    const float* __restrict__ x, ushort_t* __restrict__ hi,
    ushort_t* __restrict__ lo, int n4)
{
    int i = blockIdx.x * 256 + threadIdx.x;
    if (i >= n4) return;
    float4 v = ((const float4*)x)[i];
    ushort_t h0,h1,h2,h3,l0,l1,l2,l3;
    split1(v.x,h0,l0); split1(v.y,h1,l1); split1(v.z,h2,l2); split1(v.w,h3,l3);
    ushort_t* hp = hi + (size_t)i*4;  hp[0]=h0; hp[1]=h1; hp[2]=h2; hp[3]=h3;
    ushort_t* lp = lo + (size_t)i*4;  lp[0]=l0; lp[1]=l1; lp[2]=l2; lp[3]=l3;
}

// ---------------- async global->LDS 16B ----------------
__device__ inline void gld16(const ushort_t* g, void* l) {
    __builtin_amdgcn_global_load_lds(
        (const __attribute__((address_space(1))) void*)(const void*)g,
        (__attribute__((address_space(3))) void*)l, 16, 0, 0);
}

// ---------------- bf16x3 MFMA GEMM: C = (Ah+Al)@(Bh+Bl)^T (+bias) ----------------
// A: [M][lda] bf16 hi/lo, B: [N][ldw] bf16 hi/lo, C fp32.
// M,N multiples of 128. kchunks>1 => write partials C[kc][M][N] (no bias).
// gridDim.z == kchunks (single) or 2*kchunks (dual: second set of operands).
__global__ __launch_bounds__(256) void gemm_x3(
    const ushort_t* __restrict__ Ah, const ushort_t* __restrict__ Al, int lda,
    const ushort_t* __restrict__ Bh, const ushort_t* __restrict__ Bl, int ldw,
    const float* __restrict__ bias,
    float* __restrict__ C,
    int M, int N, int K, int kchunks,
    const ushort_t* __restrict__ A2h, const ushort_t* __restrict__ A2l,
    const ushort_t* __restrict__ B2h, const ushort_t* __restrict__ B2l,
    float* __restrict__ C2)
{
    int z = blockIdx.z;
    int kc = z;
    if (z >= kchunks) { kc = z - kchunks; Ah=A2h; Al=A2l; Bh=B2h; Bl=B2l; C=C2; }

    __shared__ ushort_t sAh[2][128*32], sAl[2][128*32];
    __shared__ ushort_t sBh[2][128*32], sBl[2][128*32];

    const int tid  = threadIdx.x;
    const int bm   = blockIdx.y * 128, bn = blockIdx.x * 128;
    const int wave = tid >> 6, lane = tid & 63;
    const int wr   = (wave >> 1) * 64, wc = (wave & 1) * 64;
    const int r    = lane & 15, g = lane >> 4;

    fx4 acc[4][4] = {};

    const int kper = K / kchunks;
    const int kbeg = kc * kper;
    const int nt   = kper / 32;

#define STAGE(buf, k0)                                                        \
    {                                                                         \
      _Pragma("unroll")                                                       \
      for (int i_ = 0; i_ < 2; ++i_) {                                        \
        const int o_   = (tid + i_*256) * 16;   /* byte offset in 8kB tile */ \
        const int row_ = o_ >> 6;                                             \
        const int el_  = (o_ & 63) >> 1;                                      \
        const size_t ga_ = (size_t)(bm + row_) * lda + (k0) + el_;            \
        const size_t gb_ = (size_t)(bn + row_) * ldw + (k0) + el_;            \
        const int lb_ = (wave*64 + i_*256) * 16; /* wave-uniform LDS base */  \
        gld16(Ah + ga_, (char*)&sAh[buf][0] + lb_);                           \
        gld16(Al + ga_, (char*)&sAl[buf][0] + lb_);                           \
        gld16(Bh + gb_, (char*)&sBh[buf][0] + lb_);                           \
        gld16(Bl + gb_, (char*)&sBl[buf][0] + lb_);                           \
      }                                                                       \
    }

    int cur = 0;
    STAGE(0, kbeg)
    __syncthreads();

    for (int t = 0; t < nt; ++t) {
        if (t + 1 < nt) STAGE(cur ^ 1, kbeg + (t+1)*32)

        s16x8 a_h[4], a_l[4], b_h[4], b_l[4];
#pragma unroll
        for (int i = 0; i < 4; ++i) {
            const int ao = (wr + i*16 + r)*32 + g*8;
            const int bo = (wc + i*16 + r)*32 + g*8;
            a_h[i] = *(const s16x8*)&sAh[cur][ao];
            a_l[i] = *(const s16x8*)&sAl[cur][ao];
            b_h[i] = *(const s16x8*)&sBh[cur][bo];
            b_l[i] = *(const s16x8*)&sBl[cur][bo];
        }
#pragma unroll
        for (int i = 0; i < 4; ++i)
#pragma unroll
            for (int j = 0; j < 4; ++j) {
                acc[i][j] = __builtin_amdgcn_mfma_f32_16x16x32_bf16(a_h[i], b_h[j], acc[i][j], 0, 0, 0);
                acc[i][j] = __builtin_amdgcn_mfma_f32_16x16x32_bf16(a_l[i], b_h[j], acc[i][j], 0, 0, 0);
                acc[i][j] = __builtin_amdgcn_mfma_f32_16x16x32_bf16(a_h[i], b_l[j], acc[i][j], 0, 0, 0);
            }
        __syncthreads();
        cur ^= 1;
    }
#undef STAGE

    float* Cw = C + (size_t)kc * M * N;
#pragma unroll
    for (int i = 0; i < 4; ++i)
#pragma unroll
        for (int j = 0; j < 4; ++j)
#pragma unroll
            for (int reg = 0; reg < 4; ++reg) {
                const int row = bm + wr + i*16 + g*4 + reg;
                const int col = bn + wc + j*16 + r;
                float v = acc[i][j][reg];
                if (kchunks == 1 && bias) v += bias[col];
                Cw[(size_t)row * N + col] = v;
            }
}

// ---------------- fp32 tiled GEMM (full-K, N-guarded) — logits only ----------------
#define BM 64
#define BN 64
#define BK 16

__global__ __launch_bounds__(256) void gemm_wt(
    const float* __restrict__ A, int lda,
    const float* __restrict__ W, int ldw,
    const float* __restrict__ bias,
    float* __restrict__ C, int ldc,
    int M, int N, int K)
{
    __shared__ float As[BK][BM];
    __shared__ float Ws[BK][BN];
    const int tid = threadIdx.x;
    const int bm = blockIdx.y * BM;
    const int bn = blockIdx.x * BN;
    const int lr = tid >> 2;
    const int lc = (tid & 3) << 2;
    const int tr = (tid >> 4) << 2;
    const int tc = (tid & 15) << 2;

    float acc[4][4] = {};
    for (int k0 = 0; k0 < K; k0 += BK) {
        {
            const int gr = bm + lr;
            float4 av = *(const float4*)(A + (size_t)gr * lda + k0 + lc);
            As[lc+0][lr] = av.x; As[lc+1][lr] = av.y;
            As[lc+2][lr] = av.z; As[lc+3][lr] = av.w;
            const int wr2 = bn + lr;
            float4 wv = make_float4(0.f,0.f,0.f,0.f);
            if (wr2 < N) wv = *(const float4*)(W + (size_t)wr2 * ldw + k0 + lc);
            Ws[lc+0][lr] = wv.x; Ws[lc+1][lr] = wv.y;
            Ws[lc+2][lr] = wv.z; Ws[lc+3][lr] = wv.w;
        }
        __syncthreads();
#pragma unroll
        for (int k = 0; k < BK; ++k) {
            float4 a4 = *(const float4*)&As[k][tr];
            float4 b4 = *(const float4*)&Ws[k][tc];
            float ar[4] = {a4.x,a4.y,a4.z,a4.w};
            float br[4] = {b4.x,b4.y,b4.z,b4.w};
#pragma unroll
            for (int i = 0; i < 4; ++i)
#pragma unroll
                for (int j = 0; j < 4; ++j)
                    acc[i][j] = fmaf(ar[i], br[j], acc[i][j]);
        }
        __syncthreads();
    }
#pragma unroll
    for (int i = 0; i < 4; ++i) {
        const int m = bm + tr + i;
#pragma unroll
        for (int j = 0; j < 4; ++j) {
            const int n = bn + tc + j;
            if (n < N) C[(size_t)m * ldc + n] = acc[i][j] + bias[n];
        }
    }
}

// ---------------- GRU update (+ fused bf16 hi/lo split of new h) ----------------
// gi_nsplit==0: GI full rows (already biased), row stride gi_rstride (0 = broadcast)
// gi_nsplit==KSPLIT: GI partials [KSPLIT][B][3H] + bih
__global__ __launch_bounds__(256) void gru_update2(
    const float* __restrict__ GI, int gi_rstride, int gi_nsplit,
    const float* __restrict__ bih,
    const float* __restrict__ GHp, const float* __restrict__ bhh,
    float* __restrict__ h, ushort_t* __restrict__ hh, ushort_t* __restrict__ hl)
{
    const int idx = blockIdx.x * 256 + threadIdx.x;
    const int b = idx >> 10;
    const int j = idx & (H_ - 1);
    float ir, iz, inn;
    if (gi_nsplit == 0) {
        const float* gi = GI + (size_t)b * gi_rstride;
        ir = gi[j]; iz = gi[H_ + j]; inn = gi[2*H_ + j];
    } else {
        ir = bih[j]; iz = bih[H_ + j]; inn = bih[2*H_ + j];
        const float* p = GI + (size_t)b * G3;
#pragma unroll
        for (int s = 0; s < KSPLIT; ++s) {
            ir += p[j]; iz += p[H_ + j]; inn += p[2*H_ + j];
            p += (size_t)B_ * G3;
        }
    }
    float hr = bhh[j], hz = bhh[H_ + j], hn = bhh[2*H_ + j];
    const float* q = GHp + (size_t)b * G3;
#pragma unroll
    for (int s = 0; s < KSPLIT; ++s) {
        hr += q[j]; hz += q[H_ + j]; hn += q[2*H_ + j];
        q += (size_t)B_ * G3;
    }
    const float rg = 1.f / (1.f + expf(-(ir + hr)));
    const float zg = 1.f / (1.f + expf(-(iz + hz)));
    const float ng = tanhf(inn + rg * hn);
    const float v = (1.f - zg) * ng + zg * h[idx];
    h[idx] = v;
    split1(v, hh[idx], hl[idx]);
}

// ---------------- u = relu(sum partials + bias) -> bf16 hi/lo ----------------
__global__ __launch_bounds__(256) void relu_combine(
    const float* __restrict__ Up, const float* __restrict__ bias,
    ushort_t* __restrict__ uh, ushort_t* __restrict__ ul)
{
    const int idx = blockIdx.x * 256 + threadIdx.x;  // B*H
    const int j = idx & (H_ - 1);
    float v = bias[j];
#pragma unroll
    for (int s = 0; s < KSPLIT; ++s) v += Up[(size_t)s * B_ * H_ + idx];
    v = fmaxf(v, 0.f);
    split1(v, uh[idx], ul[idx]);
}

// ---------------- cat = [eh | embed[word]] in bf16 hi/lo ----------------
__global__ __launch_bounds__(256) void cat_eh_emb(
    const ushort_t* __restrict__ ehh, const ushort_t* __restrict__ ehl,
    const float* __restrict__ embed, const int* __restrict__ word,
    ushort_t* __restrict__ cath, ushort_t* __restrict__ catl)
{
    const int idx = blockIdx.x * 256 + threadIdx.x;  // B*2H
    const int b = idx >> 11;
    const int j = idx & (2*H_ - 1);
    if (j < H_) {
        cath[idx] = ehh[b * H_ + j];
        catl[idx] = ehl[b * H_ + j];
    } else {
        float v = embed[(size_t)word[b] * H_ + (j - H_)];
        split1(v, cath[idx], catl[idx]);
    }
}

// ---------------- init ----------------
__global__ __launch_bounds__(256) void init_state(
    float* __restrict__ eh, float* __restrict__ dh,
    ushort_t* __restrict__ ehh, ushort_t* __restrict__ ehl,
    ushort_t* __restrict__ dhh, ushort_t* __restrict__ dhl,
    int* __restrict__ word, float* __restrict__ out)
{
    const int idx = blockIdx.x * 256 + threadIdx.x;
    if (idx < B_*H_) {
        eh[idx] = 0.f; dh[idx] = 0.f;
        ehh[idx] = 0; ehl[idx] = 0; dhh[idx] = 0; dhl[idx] = 0;
    }
    if (idx < B_)    word[idx] = 1;
    if (idx < 21)    out[idx] = 0.f;
}

// ---------------- log-softmax + argmax + loss ----------------
__global__ __launch_bounds__(256) void softmax_loss(
    const float* __restrict__ logits, const int* __restrict__ target,
    int s, int* __restrict__ word, float* __restrict__ out)
{
    const int b = blockIdx.x;
    const int t = threadIdx.x;
    const float* row = logits + (size_t)b * V_;
    __shared__ float sv[256];
    __shared__ int   si[256];
    __shared__ float ss[256];

    float best = -FLT_MAX; int bi = 0;
    for (int j = t; j < V_; j += 256) {
        float v = row[j];
        if (v > best) { best = v; bi = j; }
    }
    sv[t] = best; si[t] = bi;
    __syncthreads();
    for (int off = 128; off > 0; off >>= 1) {
        if (t < off) {
            float v2 = sv[t + off]; int i2 = si[t + off];
            if (v2 > sv[t] || (v2 == sv[t] && i2 < si[t])) { sv[t] = v2; si[t] = i2; }
        }
        __syncthreads();
    }
    const float m = sv[0];
    const int amax = si[0];

    float sum = 0.f;
    for (int j = t; j < V_; j += 256) sum += expf(row[j] - m);
    ss[t] = sum;
    __syncthreads();
    for (int off = 128; off > 0; off >>= 1) {
        if (t < off) ss[t] += ss[t + off];
        __syncthreads();
    }
    if (t == 0) {
        const float lse = m + logf(ss[0]);
        const int tgt = target[b * S_ + s];
        const float logp = row[tgt] - lse;
        atomicAdd(&out[0], -logp * (1.0f / (float)B_));
        word[b] = amax;
        if (b == 0) out[1 + s]  = (float)amax;
        if (b == 1) out[11 + s] = (float)amax;
    }
}

// ---------------- host helpers ----------------
static inline void launch_x3(hipStream_t st,
    const ushort_t* Ah, const ushort_t* Al, int lda,
    const ushort_t* Bh, const ushort_t* Bl, int ldw,
    const float* bias, float* C, int M, int N, int K, int kchunks)
{
    dim3 grid(N/128, M/128, kchunks);
    gemm_x3<<<grid, 256, 0, st>>>(Ah, Al, lda, Bh, Bl, ldw, bias, C, M, N, K, kchunks,
                                  nullptr, nullptr, nullptr, nullptr, nullptr);
}

static inline void launch_x3_dual(hipStream_t st,
    const ushort_t* Ah, const ushort_t* Al,
    const ushort_t* Bh, const ushort_t* Bl, float* C,
    const ushort_t* A2h, const ushort_t* A2l,
    const ushort_t* B2h, const ushort_t* B2l, float* C2,
    int M, int N, int K, int kchunks)
{
    dim3 grid(N/128, M/128, 2*kchunks);
    gemm_x3<<<grid, 256, 0, st>>>(Ah, Al, H_, Bh, Bl, H_, nullptr, C, M, N, K, kchunks,
                                  A2h, A2l, B2h, B2l, C2);
}

extern "C" void kernel_launch(void* const* d_in, const int* in_sizes, int n_in,
                              void* d_out, int out_size, void* d_ws, size_t ws_size,
                              hipStream_t stream)
{
    const float* data    = (const float*)d_in[0];
    const int*   target  = (const int*)  d_in[2];
    const float* enc_Wih = (const float*)d_in[4];
    const float* enc_Whh = (const float*)d_in[5];
    const float* enc_bih = (const float*)d_in[6];
    const float* enc_bhh = (const float*)d_in[7];
    const float* dec_Wih = (const float*)d_in[8];
    const float* dec_Whh = (const float*)d_in[9];
    const float* dec_bih = (const float*)d_in[10];
    const float* dec_bhh = (const float*)d_in[11];
    const float* lin1_W  = (const float*)d_in[12];
    const float* lin1_b  = (const float*)d_in[13];
    const float* lin2_W  = (const float*)d_in[14];
    const float* lin2_b  = (const float*)d_in[15];
    const float* embed   = (const float*)d_in[16];
    float* out = (float*)d_out;

    float *gi, *eh, *dh, *logits, *ghp, *gi2p, *gh2p, *up;
    ushort_t *Ah, *Al, *Bh, *Bl, *Whh_h, *Whh_l, *dWih_h, *dWih_l, *dWhh_h, *dWhh_l;
    ushort_t *l1h, *l1l, *ehh, *ehl, *dhh, *dhl, *uh, *ul, *cath, *catl;
    int* word;
    hipGetSymbolAddress((void**)&gi,     HIP_SYMBOL(g_gi));
    hipGetSymbolAddress((void**)&Ah,     HIP_SYMBOL(g_Ah));
    hipGetSymbolAddress((void**)&Al,     HIP_SYMBOL(g_Al));
    hipGetSymbolAddress((void**)&Bh,     HIP_SYMBOL(g_Bh));
    hipGetSymbolAddress((void**)&Bl,     HIP_SYMBOL(g_Bl));
    hipGetSymbolAddress((void**)&Whh_h,  HIP_SYMBOL(g_Whh_h));
    hipGetSymbolAddress((void**)&Whh_l,  HIP_SYMBOL(g_Whh_l));
    hipGetSymbolAddress((void**)&dWih_h, HIP_SYMBOL(g_dWih_h));
    hipGetSymbolAddress((void**)&dWih_l, HIP_SYMBOL(g_dWih_l));
    hipGetSymbolAddress((void**)&dWhh_h, HIP_SYMBOL(g_dWhh_h));
    hipGetSymbolAddress((void**)&dWhh_l, HIP_SYMBOL(g_dWhh_l));
    hipGetSymbolAddress((void**)&l1h,    HIP_SYMBOL(g_l1h));
    hipGetSymbolAddress((void**)&l1l,    HIP_SYMBOL(g_l1l));
    hipGetSymbolAddress((void**)&ghp,    HIP_SYMBOL(g_ghp));
    hipGetSymbolAddress((void**)&gi2p,   HIP_SYMBOL(g_gi2p));
    hipGetSymbolAddress((void**)&gh2p,   HIP_SYMBOL(g_gh2p));
    hipGetSymbolAddress((void**)&up,     HIP_SYMBOL(g_up));
    hipGetSymbolAddress((void**)&eh,     HIP_SYMBOL(g_eh));
    hipGetSymbolAddress((void**)&dh,     HIP_SYMBOL(g_dh));
    hipGetSymbolAddress((void**)&ehh,    HIP_SYMBOL(g_ehh));
    hipGetSymbolAddress((void**)&ehl,    HIP_SYMBOL(g_ehl));
    hipGetSymbolAddress((void**)&dhh,    HIP_SYMBOL(g_dhh));
    hipGetSymbolAddress((void**)&dhl,    HIP_SYMBOL(g_dhl));
    hipGetSymbolAddress((void**)&uh,     HIP_SYMBOL(g_uh));
    hipGetSymbolAddress((void**)&ul,     HIP_SYMBOL(g_ul));
    hipGetSymbolAddress((void**)&cath,   HIP_SYMBOL(g_cath));
    hipGetSymbolAddress((void**)&catl,   HIP_SYMBOL(g_catl));
    hipGetSymbolAddress((void**)&logits, HIP_SYMBOL(g_logits));
    hipGetSymbolAddress((void**)&word,   HIP_SYMBOL(g_word));

    init_state<<<512, 256, 0, stream>>>(eh, dh, ehh, ehl, dhh, dhl, word, out);

    // bf16 hi/lo splits (inputs + all recurrent weights)
    split_bf16<<<(B_*T_*D_/4 + 255)/256, 256, 0, stream>>>(data,    Ah, Al, B_*T_*D_/4);
    split_bf16<<<(G3*D_/4   + 255)/256, 256, 0, stream>>>(enc_Wih, Bh, Bl, G3*D_/4);
    split_bf16<<<(G3*H_/4   + 255)/256, 256, 0, stream>>>(enc_Whh, Whh_h, Whh_l, G3*H_/4);
    split_bf16<<<(G3*H_/4   + 255)/256, 256, 0, stream>>>(dec_Wih, dWih_h, dWih_l, G3*H_/4);
    split_bf16<<<(G3*H_/4   + 255)/256, 256, 0, stream>>>(dec_Whh, dWhh_h, dWhh_l, G3*H_/4);
    split_bf16<<<(H_*2*H_/4 + 255)/256, 256, 0, stream>>>(lin1_W,  l1h, l1l, H_*2*H_/4);

    // gi[B*T][3H] = data @ enc_Wih^T + enc_bih
    launch_x3(stream, Ah, Al, D_, Bh, Bl, D_, enc_bih, gi, B_*T_, G3, D_, 1);

    // ---------------- encoder scan ----------------
    for (int t = 0; t < T_; ++t) {
        launch_x3(stream, ehh, ehl, H_, Whh_h, Whh_l, H_, nullptr, ghp, B_, G3, H_, KSPLIT);
        gru_update2<<<512, 256, 0, stream>>>(gi + (size_t)t * G3, T_ * G3, 0, nullptr,
                                             ghp, enc_bhh, eh, ehh, ehl);
        launch_x3(stream, ehh, ehl, H_, l1h, l1l, 2*H_, nullptr, up, B_, H_, H_, KSPLIT);
        relu_combine<<<512, 256, 0, stream>>>(up, lin1_b, uh, ul);
        launch_x3_dual(stream, uh, ul, dWih_h, dWih_l, gi2p,
                               dhh, dhl, dWhh_h, dWhh_l, gh2p, B_, G3, H_, KSPLIT);
        gru_update2<<<512, 256, 0, stream>>>(gi2p, 0, KSPLIT, dec_bih,
                                             gh2p, dec_bhh, dh, dhh, dhl);
    }

    // ---------------- decoder scan ----------------
    for (int s = 0; s < S_; ++s) {
        launch_x3(stream, ehh, ehl, H_, Whh_h, Whh_l, H_, nullptr, ghp, B_, G3, H_, KSPLIT);
        gru_update2<<<512, 256, 0, stream>>>(enc_bih, 0, 0, nullptr,
                                             ghp, enc_bhh, eh, ehh, ehl);
        cat_eh_emb<<<1024, 256, 0, stream>>>(ehh, ehl, embed, word, cath, catl);
        launch_x3(stream, cath, catl, 2*H_, l1h, l1l, 2*H_, nullptr, up, B_, H_, 2*H_, KSPLIT);
        relu_combine<<<512, 256, 0, stream>>>(up, lin1_b, uh, ul);
        launch_x3_dual(stream, uh, ul, dWih_h, dWih_l, gi2p,
                               dhh, dhl, dWhh_h, dWhh_l, gh2p, B_, G3, H_, KSPLIT);
        gru_update2<<<512, 256, 0, stream>>>(gi2p, 0, KSPLIT, dec_bih,
                                             gh2p, dec_bhh, dh, dhh, dhl);
        { dim3 grid((V_+BN-1)/BN, B_/BM, 1);
          gemm_wt<<<grid, 256, 0, stream>>>(dh, H_, lin2_W, H_, lin2_b, logits, V_, B_, V_, H_); }
        softmax_loss<<<B_, 256, 0, stream>>>(logits, target, s, word, out);
    }
}